// Round 2
// baseline (246.808 us; speedup 1.0000x reference)
//
#include <hip/hip_runtime.h>
#include <hip/hip_bf16.h>
#include <cstdint>

typedef __attribute__((ext_vector_type(8))) __bf16 bf16x8;
typedef __attribute__((ext_vector_type(4))) __bf16 bf16x4;
typedef __attribute__((ext_vector_type(2))) __bf16 bf16x2;
typedef __attribute__((ext_vector_type(4))) float  f32x4;

#define N_IMG 3136   // 56*56
#define NB16  196    // 3136/16
#define CB8   56     // 448/8
#define P_CNT 2496   // 52*48 interior pixels
#define NDIR  34     // stencil directions

// stencil offsets dy*56+dx for RADIUS=5 (matches get_indices_of_pairs order)
__constant__ int c_offs[NDIR] = {
  1,2,3,4,
  52,53,54,55,56,57,58,59,60,
  108,109,110,111,112,113,114,115,116,
  165,166,167,168,169,170,171,
  222,223,224,225,226};

__device__ __forceinline__ void block_sync(){
  // raw barrier: LDS drained, but vector-mem loads stay in flight across it
  asm volatile("s_waitcnt lgkmcnt(0)\n\ts_barrier" ::: "memory");
}

__device__ __forceinline__ float elu_f(float v){
  return v > 0.f ? v : expm1f(v);
}

// ---------------- weight f32->bf16 prep (one launch, 4 segments) -------------
__global__ __launch_bounds__(256) void cvt_weights(
    const float* __restrict__ w83, const float* __restrict__ w84,
    const float* __restrict__ w85, const float* __restrict__ w9,
    __bf16* __restrict__ o83, __bf16* __restrict__ o84,
    __bf16* __restrict__ o85, __bf16* __restrict__ o9)
{
  int i = blockIdx.x*256 + threadIdx.x;  // index in float4 units
  const float* src; __bf16* dst; int off;
  if      (i <   8192){ src=w83; dst=o83; off=i; }
  else if (i <  40960){ src=w84; dst=o84; off=i-8192; }
  else if (i < 303104){ src=w85; dst=o85; off=i-40960; }
  else if (i < 353280){ src=w9 ; dst=o9 ; off=i-303104; }
  else return;
  f32x4 v = ((const f32x4*)src)[off];
  bf16x4 o;
  o[0]=(__bf16)v[0]; o[1]=(__bf16)v[1]; o[2]=(__bf16)v[2]; o[3]=(__bf16)v[3];
  ((bf16x4*)dst)[off] = o;
}

// ---------------- feature GEMMs: y1[n,c] = elu(W[MT x KTOT] * X[KTOT x N]) ---
// Output written in MFMA-B-fragment layout: idx = (((b*196+n/16)*56+c/8)*16+n%16)*8+c%8
template<int MT, int KTOT, int MW, int NW>
__global__ __launch_bounds__(MW*NW*64) void gemm_feat(
    const float* __restrict__ X, const __bf16* __restrict__ Wb,
    __bf16* __restrict__ y1, int c_off)
{
  constexpr int WG    = MW*NW*64;
  constexpr int NFRAG = 64/NW/16;        // 1 or 2 n-fragments per wave
  constexpr int WNS   = 64/NW;           // wave n-span
  constexpr int TPR   = WG/MT;           // threads per A row
  constexpr int ACH   = 8/TPR;           // uint4 (8-bf16) chunks per thread (A row = 8 chunks)
  constexpr int KB    = (64*64)/(WG*4);  // k-rows per thread in B transpose blk
  constexpr int NSTEP = KTOT/64;

  __shared__ __bf16 Alds[2][MT][72];   // 64 bf16 + 8 pad
  __shared__ __bf16 Blds[2][64][72];   // transposed: [n][k], padded

  const int tid  = threadIdx.x;
  const int lane = tid & 63;
  const int wid  = tid >> 6;
  const int wm   = wid / NW;
  const int wn   = wid % NW;
  const int l15  = lane & 15;
  const int l4   = lane >> 4;
  const int b    = blockIdx.y;
  const int n0   = blockIdx.x * 64;
  const float* Xb = X + (size_t)b * KTOT * N_IMG;

  const int am  = tid / TPR;   // A row handled by this thread
  const int aq0 = tid % TPR;
  const int nbk = tid & 15;    // B: n-block (4 cols) -- keeps global loads coalesced
  const int kbk = tid >> 4;    // B: k-block (KB rows)

  uint4 areg[ACH];
  f32x4 breg[KB];
  f32x4 acc[4][NFRAG];
  const f32x4 fz = {0.f,0.f,0.f,0.f};
  #pragma unroll
  for (int mi=0; mi<4; ++mi)
    #pragma unroll
    for (int ni=0; ni<NFRAG; ++ni) acc[mi][ni] = fz;

  // prologue: issue loads for step 0 (chunk = 8 bf16 = one uint4)
  #pragma unroll
  for (int i=0;i<ACH;++i)
    areg[i] = *(const uint4*)(Wb + (size_t)am*KTOT + (aq0*ACH + i)*8);
  #pragma unroll
  for (int r=0;r<KB;++r)
    breg[r] = *(const f32x4*)(Xb + (size_t)(kbk*KB + r)*N_IMG + n0 + nbk*4);

  for (int s=0; s<NSTEP; ++s){
    const int buf = s & 1;
    // ---- stage current tile into LDS (cvt + transpose for B) ----
    #pragma unroll
    for (int i=0;i<ACH;++i)
      *(uint4*)&Alds[buf][am][(aq0*ACH + i)*8] = areg[i];
    #pragma unroll
    for (int j=0;j<4;++j){
      if constexpr (KB==4){
        bf16x4 v;
        v[0]=(__bf16)breg[0][j]; v[1]=(__bf16)breg[1][j];
        v[2]=(__bf16)breg[2][j]; v[3]=(__bf16)breg[3][j];
        *(bf16x4*)&Blds[buf][nbk*4+j][kbk*4] = v;
      } else {
        bf16x2 v;
        v[0]=(__bf16)breg[0][j]; v[1]=(__bf16)breg[1][j];
        *(bf16x2*)&Blds[buf][nbk*4+j][kbk*2] = v;
      }
    }
    // ---- prefetch next tile (flies across the barrier / compute) ----
    if (s+1 < NSTEP){
      const int k0 = (s+1)*64;
      #pragma unroll
      for (int i=0;i<ACH;++i)
        areg[i] = *(const uint4*)(Wb + (size_t)am*KTOT + k0 + (aq0*ACH + i)*8);
      #pragma unroll
      for (int r=0;r<KB;++r)
        breg[r] = *(const f32x4*)(Xb + (size_t)(k0 + kbk*KB + r)*N_IMG + n0 + nbk*4);
    }
    block_sync();   // one barrier/iter is sufficient (alternating buffers)
    // ---- compute ----
    #pragma unroll
    for (int kk=0; kk<2; ++kk){
      bf16x8 av[4];
      #pragma unroll
      for (int mi=0; mi<4; ++mi)
        av[mi] = *(const bf16x8*)&Alds[buf][wm*64 + mi*16 + l15][kk*32 + l4*8];
      #pragma unroll
      for (int ni=0; ni<NFRAG; ++ni){
        bf16x8 bv = *(const bf16x8*)&Blds[buf][wn*WNS + ni*16 + l15][kk*32 + l4*8];
        #pragma unroll
        for (int mi=0; mi<4; ++mi)
          acc[mi][ni] = __builtin_amdgcn_mfma_f32_16x16x32_bf16(av[mi], bv, acc[mi][ni], 0,0,0);
      }
    }
  }

  // ---- epilogue: elu + store to fragment layout ----
  #pragma unroll
  for (int mi=0; mi<4; ++mi){
    const int c0 = c_off + wm*64 + mi*16 + l4*4;  // 4 consecutive channels
    const int cb = c0 >> 3;
    const int jj = c0 & 7;
    #pragma unroll
    for (int ni=0; ni<NFRAG; ++ni){
      const int n = n0 + wn*WNS + ni*16 + l15;
      size_t idx = ((((size_t)b*NB16 + (n>>4))*CB8 + cb)*16 + (n&15))*8 + jj;
      f32x4 a = acc[mi][ni];
      bf16x4 o;
      #pragma unroll
      for (int r=0;r<4;++r) o[r] = (__bf16)elu_f(a[r]);
      *(bf16x4*)(y1 + idx) = o;
    }
  }
}

// ---------------- output GEMM: x2[n, o] = elu(w9[448x448] * y1) -------------
__global__ __launch_bounds__(256) void gemm_out(
    const __bf16* __restrict__ y1, const __bf16* __restrict__ w9b,
    __bf16* __restrict__ x2)
{
  const int nt = blockIdx.x, mt = blockIdx.y, b = blockIdx.z;
  const int tid = threadIdx.x;
  if (mt == 7){
    // zero the pad columns 448..511 of this n-tile
    const int row = tid >> 2, q = tid & 3;
    __bf16* p = x2 + ((size_t)b*N_IMG + nt*64 + row)*512 + 448 + q*16;
    uint4 z = {0u,0u,0u,0u};
    *(uint4*)p = z;
    *(uint4*)(p+8) = z;
    return;
  }
  __shared__ __bf16 Alds[2][64][72];
  const int lane = tid & 63, wid = tid >> 6;
  const int l15 = lane & 15, l4 = lane >> 4;
  const int am = tid >> 2, aq = tid & 3;    // 4 threads/row, 2 uint4 chunks each
  // each wave owns one 16-col block of y1's fragment layout
  const __bf16* Bbase = y1 + ((size_t)b*NB16 + nt*4 + wid)*CB8*128;
  f32x4 acc[4];
  const f32x4 fz = {0.f,0.f,0.f,0.f};
  #pragma unroll
  for (int mi=0;mi<4;++mi) acc[mi] = fz;

  uint4 areg[2];
  #pragma unroll
  for (int i=0;i<2;++i)
    areg[i] = *(const uint4*)(w9b + (size_t)(mt*64 + am)*448 + (aq*2+i)*8);
  for (int s=0;s<7;++s){
    const int buf = s&1;
    #pragma unroll
    for (int i=0;i<2;++i)
      *(uint4*)&Alds[buf][am][(aq*2+i)*8] = areg[i];
    if (s<6){
      #pragma unroll
      for (int i=0;i<2;++i)
        areg[i] = *(const uint4*)(w9b + (size_t)(mt*64+am)*448 + (s+1)*64 + (aq*2+i)*8);
    }
    block_sync();
    #pragma unroll
    for (int kk=0;kk<2;++kk){
      const int kc = s*2+kk;
      bf16x8 bv = *(const bf16x8*)(Bbase + kc*512 + lane*8);  // linear lane*16B
      #pragma unroll
      for (int mi=0;mi<4;++mi){
        bf16x8 av = *(const bf16x8*)&Alds[buf][mi*16 + l15][kk*32 + l4*8];
        acc[mi] = __builtin_amdgcn_mfma_f32_16x16x32_bf16(av, bv, acc[mi], 0,0,0);
      }
    }
  }
  #pragma unroll
  for (int mi=0;mi<4;++mi){
    const int o = mt*64 + mi*16 + l4*4;
    const int n = nt*64 + wid*16 + l15;
    f32x4 a = acc[mi];
    bf16x4 v;
    #pragma unroll
    for (int r=0;r<4;++r) v[r] = (__bf16)elu_f(a[r]);
    *(bf16x4*)(x2 + ((size_t)b*N_IMG + n)*512 + o) = v;
  }
}

// ---------------- affinity stencil: one wave per (b, p) ---------------------
__global__ __launch_bounds__(256) void affinity_kernel(
    const __bf16* __restrict__ x2, float* __restrict__ out)
{
  const int b = blockIdx.x;                 // b fastest -> each XCD sees one batch
  const int lane = threadIdx.x & 63, wid = threadIdx.x >> 6;
  const int p = blockIdx.y*4 + wid;
  const int from = (p/48)*56 + 4 + (p%48);
  const __bf16* xb = x2 + (size_t)b*N_IMG*512;
  bf16x8 ffv = *(const bf16x8*)(xb + (size_t)from*512 + lane*8);
  float ff[8];
  #pragma unroll
  for (int j=0;j<8;++j) ff[j] = (float)ffv[j];
  for (int d=0; d<NDIR; ++d){
    const int to = from + c_offs[d];
    bf16x8 ftv = *(const bf16x8*)(xb + (size_t)to*512 + lane*8);
    float s = 0.f;
    #pragma unroll
    for (int j=0;j<8;++j) s += fabsf(ff[j] - (float)ftv[j]);
    #pragma unroll
    for (int m=1;m<64;m<<=1) s += __shfl_xor(s, m, 64);
    if (lane == 0) out[((size_t)b*NDIR + d)*P_CNT + p] = expf(-s*(1.f/448.f));
  }
}

extern "C" void kernel_launch(void* const* d_in, const int* in_sizes, int n_in,
                              void* d_out, int out_size, void* d_ws, size_t ws_size,
                              hipStream_t stream)
{
  (void)in_sizes; (void)n_in; (void)out_size; (void)ws_size;
  const float* conv4 = (const float*)d_in[0];
  const float* conv5 = (const float*)d_in[1];
  const float* conv6 = (const float*)d_in[2];
  const float* w83   = (const float*)d_in[3];
  const float* w84   = (const float*)d_in[4];
  const float* w85   = (const float*)d_in[5];
  const float* w9    = (const float*)d_in[6];
  // ind_from / ind_to (d_in[7], d_in[8]) are recomputed on device (hardcoded stencil)
  float* out = (float*)d_out;
  char* ws = (char*)d_ws;
  // workspace layout (26,910,720 bytes total)
  __bf16* w83b = (__bf16*)(ws + 0);         //  64x512
  __bf16* w84b = (__bf16*)(ws + 65536);     // 128x1024
  __bf16* w85b = (__bf16*)(ws + 327680);    // 256x4096
  __bf16* w9b  = (__bf16*)(ws + 2424832);   // 448x448
  __bf16* y1   = (__bf16*)(ws + 2826240);   // 4*3136*448, fragment layout
  __bf16* x2   = (__bf16*)(ws + 14065664);  // 4*3136*512 (448 + zero pad)

  cvt_weights<<<1380, 256, 0, stream>>>(w83,w84,w85,w9, w83b,w84b,w85b,w9b);
  gemm_feat< 64,  512, 1, 4><<<dim3(49,4), 256, 0, stream>>>(conv4, w83b, y1, 0);
  gemm_feat<128, 1024, 2, 2><<<dim3(49,4), 256, 0, stream>>>(conv5, w84b, y1, 64);
  gemm_feat<256, 4096, 4, 2><<<dim3(49,4), 512, 0, stream>>>(conv6, w85b, y1, 192);
  gemm_out<<<dim3(49,8,4), 256, 0, stream>>>(y1, w9b, x2);
  affinity_kernel<<<dim3(4,624), 256, 0, stream>>>(x2, out);
}